// Round 3
// baseline (2598.710 us; speedup 1.0000x reference)
//
#include <hip/hip_runtime.h>
#include <cstdint>

// Instant-NGP hash-grid encoder, D=3, L=16, C=2, H=16, PS=2, T=2^19.
// Round-3: gather is L2-request-rate bound (933us ~= 268M reqs / 8 XCD /
// 16 req/cyc = 873us; HBM 14%, VALU 9%). Cut L2 requests via x-pair line
// fusion: every corner loads float4 at pair-index (i>>1) and selects
// .xy/.zw by parity. Fused pairs (hashed: ix even -> i1=i0^1; dense: i0
// even -> i1=i0+1) issue two IDENTICAL addresses back-to-back -> second is
// an L1/MSHR hit, zero L2 cost. Branchless, same instruction count.
// Level-major grid + XCD pinning (blockIdx%8) keeps one <=4MB table per
// XCD L2 (round-2 win: FETCH 4.84GB -> 0.79GB).
// NUMERICS: pos = x01*scale + 0.5 must be two separately-rounded f32 ops
// (numpy semantics); __fmul_rn/__fadd_rn block FMA contraction there.

static constexpr uint32_t PRIME1 = 2654435761u;
static constexpr uint32_t PRIME2 = 805459861u;
static constexpr uint32_t HASH_MASK = (1u << 19) - 1u;

__constant__ uint32_t c_offs[16] = {
    0u, 4920u, 40864u, 315496u, 839784u, 1364072u, 1888360u, 2412648u,
    2936936u, 3461224u, 3985512u, 4509800u, 5034088u, 5558376u,
    6082664u, 6606952u};

__global__ __launch_bounds__(256) void gather_kernel(
    const float* __restrict__ inputs,      // [B,3]
    const float* __restrict__ embeddings,  // [4920,2] (level-0 rows)
    const float* __restrict__ table,       // [TOTAL-4920,2]
    float2* __restrict__ dst,              // staged: ws[l*B + b] ; direct: out_f2[b*16 + l]
    int B, int chunks, int directOut)
{
    // --- block -> (level, chunk) with XCD pinning ---
    const int j   = blockIdx.x;
    const int xcd = j & 7;
    const int s   = j >> 3;
    const int lvl = 2 * xcd + (s >= chunks ? 1 : 0);
    const int chunk = (s >= chunks) ? (s - chunks) : s;
    const int base  = chunk * 1024;           // 4 points/thread * 256 threads
    const int tid   = threadIdx.x;

    // --- stage this chunk's inputs through LDS (coalesced) ---
    __shared__ float sIn[3072];
    {
        const float* gp = inputs + (size_t)base * 3;
        const int lim = B * 3 - base * 3;
#pragma unroll
        for (int k = 0; k < 12; ++k) {
            const int i = tid + k * 256;
            if (i < lim) sIn[i] = gp[i];
        }
    }
    __syncthreads();

    // --- level-dependent constants (block-uniform) ---
    const float scale = (float)((16u << lvl) - 1u);   // exactly representable
    const uint32_t off = c_offs[lvl];
    const float2* __restrict__ tb = (lvl == 0)
        ? (const float2*)embeddings
        : ((const float2*)table) + (off - 4920u);
    const float4* __restrict__ tb4 = (const float4*)tb;  // 64B-aligned (offs%8==0)
    const bool dense = (lvl < 3);
    const uint32_t dstr  = (16u << lvl) + 1u;   // dense row stride
    const uint32_t dstr2 = dstr * dstr;

    uint32_t idx[4][8];
    float wts[4][8];

#pragma unroll
    for (int p = 0; p < 4; ++p) {
        const int li = p * 256 + tid;           // local point index
        // bound=1: x01=(x+1)/2 (add rounds once, *0.5 exact)
        const float x01 = __fadd_rn(sIn[li * 3 + 0], 1.0f) * 0.5f;
        const float y01 = __fadd_rn(sIn[li * 3 + 1], 1.0f) * 0.5f;
        const float z01 = __fadd_rn(sIn[li * 3 + 2], 1.0f) * 0.5f;

        // pos = x01*scale + 0.5 : two separately-rounded ops (NO fma)
        const float px = __fadd_rn(__fmul_rn(x01, scale), 0.5f);
        const float py = __fadd_rn(__fmul_rn(y01, scale), 0.5f);
        const float pz = __fadd_rn(__fmul_rn(z01, scale), 0.5f);

        const float fxf = floorf(px), fyf = floorf(py), fzf = floorf(pz);
        const float tx = px - fxf, ty = py - fyf, tz = pz - fzf;  // exact
        const uint32_t ix = (uint32_t)fxf, iy = (uint32_t)fyf, iz = (uint32_t)fzf;
        const float wx0 = 1.0f - tx, wy0 = 1.0f - ty, wz0 = 1.0f - tz;

        if (dense) {
            const uint32_t oy0 = iy * dstr,  oy1 = oy0 + dstr;
            const uint32_t oz0 = iz * dstr2, oz1 = oz0 + dstr2;
            idx[p][0] = ix + oy0 + oz0;  idx[p][1] = idx[p][0] + 1u;
            idx[p][2] = ix + oy1 + oz0;  idx[p][3] = idx[p][2] + 1u;
            idx[p][4] = ix + oy0 + oz1;  idx[p][5] = idx[p][4] + 1u;
            idx[p][6] = ix + oy1 + oz1;  idx[p][7] = idx[p][6] + 1u;
        } else {
            const uint32_t hy0 = iy * PRIME1, hy1 = hy0 + PRIME1;  // u32 wrap
            const uint32_t hz0 = iz * PRIME2, hz1 = hz0 + PRIME2;
            const uint32_t a00 = hy0 ^ hz0, a10 = hy1 ^ hz0;
            const uint32_t a01 = hy0 ^ hz1, a11 = hy1 ^ hz1;
            idx[p][0] = (ix ^ a00) & HASH_MASK;  idx[p][1] = ((ix + 1u) ^ a00) & HASH_MASK;
            idx[p][2] = (ix ^ a10) & HASH_MASK;  idx[p][3] = ((ix + 1u) ^ a10) & HASH_MASK;
            idx[p][4] = (ix ^ a01) & HASH_MASK;  idx[p][5] = ((ix + 1u) ^ a01) & HASH_MASK;
            idx[p][6] = (ix ^ a11) & HASH_MASK;  idx[p][7] = ((ix + 1u) ^ a11) & HASH_MASK;
        }

        // weights: ((x)*(y))*(z) product order matches jnp.prod
        const float wxy00 = __fmul_rn(wx0, wy0), wxy10 = __fmul_rn(tx, wy0);
        const float wxy01 = __fmul_rn(wx0, ty),  wxy11 = __fmul_rn(tx, ty);
        wts[p][0] = __fmul_rn(wxy00, wz0); wts[p][1] = __fmul_rn(wxy10, wz0);
        wts[p][2] = __fmul_rn(wxy01, wz0); wts[p][3] = __fmul_rn(wxy11, wz0);
        wts[p][4] = __fmul_rn(wxy00, tz);  wts[p][5] = __fmul_rn(wxy10, tz);
        wts[p][6] = __fmul_rn(wxy01, tz);  wts[p][7] = __fmul_rn(wxy11, tz);
    }

    // --- gathers: float4 at pair-index, select half by parity.
    //     Fused x-pairs produce two identical addresses back-to-back ->
    //     second is an L1/MSHR dedup hit (no L2 request). ---
#pragma unroll
    for (int p = 0; p < 4; ++p) {
        float4 q[8];
#pragma unroll
        for (int c = 0; c < 8; ++c)
            q[c] = tb4[idx[p][c] >> 1];

        const int b = base + p * 256 + tid;
        if (b >= B) continue;

        float r0 = 0.f, r1 = 0.f;
#pragma unroll
        for (int c = 0; c < 8; ++c) {
            const bool hi = (idx[p][c] & 1u) != 0u;
            const float ex = hi ? q[c].z : q[c].x;
            const float ey = hi ? q[c].w : q[c].y;
            if (c == 0) {
                r0 = __fmul_rn(wts[p][0], ex);
                r1 = __fmul_rn(wts[p][0], ey);
            } else {
                r0 = fmaf(wts[p][c], ex, r0);
                r1 = fmaf(wts[p][c], ey, r1);
            }
        }

        if (directOut) {
            dst[(size_t)b * 16 + lvl] = make_float2(r0, r1);
        } else {
            dst[(size_t)lvl * B + b] = make_float2(r0, r1);
        }
    }
}

// ws[16][B] float2 (level-major)  ->  out[B][32] float (point-major)
__global__ __launch_bounds__(256) void transpose_kernel(
    const float2* __restrict__ ws, float* __restrict__ out, int B)
{
    __shared__ float sT[256 * 34];   // pad +2 floats: 2-way LDS aliasing only
    const int tid = threadIdx.x;
    const int b0  = blockIdx.x * 256;

#pragma unroll
    for (int l = 0; l < 16; ++l) {
        const int b = b0 + tid;
        float2 v = make_float2(0.f, 0.f);
        if (b < B) v = ws[(size_t)l * B + b];
        sT[tid * 34 + 2 * l]     = v.x;
        sT[tid * 34 + 2 * l + 1] = v.y;
    }
    __syncthreads();

    float2* orow = (float2*)(out + (size_t)b0 * 32);
    const int lim = (B - b0) * 16;          // valid float2 count in tile
#pragma unroll
    for (int it = 0; it < 16; ++it) {
        const int f = it * 256 + tid;       // float2 index within tile
        if (f < lim) {
            const int p = f >> 4;           // point within tile
            const int c = (f & 15) * 2;     // float column
            orow[f] = make_float2(sT[p * 34 + c], sT[p * 34 + c + 1]);
        }
    }
}

extern "C" void kernel_launch(void* const* d_in, const int* in_sizes, int n_in,
                              void* d_out, int out_size, void* d_ws, size_t ws_size,
                              hipStream_t stream) {
    const float* inputs     = (const float*)d_in[0];
    const float* embeddings = (const float*)d_in[1];
    const float* table      = (const float*)d_in[2];
    float* out              = (float*)d_out;

    const int B = in_sizes[0] / 3;
    const int chunks = (B + 1023) / 1024;
    const size_t need = (size_t)16 * (size_t)B * sizeof(float2);
    const bool staged = ws_size >= need;

    gather_kernel<<<16 * chunks, 256, 0, stream>>>(
        inputs, embeddings, table,
        staged ? (float2*)d_ws : (float2*)d_out,
        B, chunks, staged ? 0 : 1);

    if (staged) {
        transpose_kernel<<<(B + 255) / 256, 256, 0, stream>>>(
            (const float2*)d_ws, out, B);
    }
}